// Round 6
// baseline (417.197 us; speedup 1.0000x reference)
//
#include <hip/hip_runtime.h>
#include <hip/hip_cooperative_groups.h>

namespace cg = cooperative_groups;

typedef unsigned int   u32;
typedef unsigned short u16;
typedef short bf16x8 __attribute__((ext_vector_type(8)));
typedef float f32x4  __attribute__((ext_vector_type(4)));

#define GAS(p) ((const __attribute__((address_space(1))) void*)(p))
#define LAS(p) ((__attribute__((address_space(3))) void*)(p))

__device__ __forceinline__ u16 f2bf(float f) {
  union { float f; u32 u; } v; v.f = f;
  u32 r = v.u + 0x7fffu + ((v.u >> 16) & 1u);
  return (u16)(r >> 16);
}
__device__ __forceinline__ u32 pack2(float a, float b) {
  return (u32)f2bf(a) | ((u32)f2bf(b) << 16);
}

// ---------------- bf16 GEMM body: C = A @ Bt^T (+epilogue) ----------------
// 8 waves (512 thr), 128x128 tile, BK=64, wave grid 2Mx4N, wave-tile 64x32.
// 2-phase dbuf, compile-time buffer indices. Proven 44.5us/579TF in round 4.
// LDS XOR-swizzle via pre-swizzled global source + swizzled ds_read (G4, r21).
#define EPI_QK_SPLIT_BF16 0
#define EPI_BIAS_ROW_BF16 1
#define EPI_SCALE_F32     2
#define EPI_BIAS_COL_F32  3
#define EPI_RESHAPE_BF16  4

template <int EPI>
__device__ __forceinline__
void gemm_body(const u16* __restrict__ Ab, int lda,
               const u16* __restrict__ Bb, int ldb,
               void* __restrict__ Cv, void* __restrict__ Cv2, long coff, int ldc,
               const float* __restrict__ bias, const float* __restrict__ bias2,
               float scale, int kTiles, long tm, long tn,
               u16* As0, u16* As1, u16* Bs0, u16* Bs1) {
  const int tid = threadIdx.x, lane = tid & 63, w = tid >> 6;
  const int wm = w >> 2, wn = w & 3;      // wave grid 2x4
  const int rl = lane >> 3;               // row-in-stripe this lane stages
  const int sl = (lane & 7) ^ rl;         // pre-swizzled 16B-slot index
  const int fr = lane & 15, fq = lane >> 4;

  const u16* gA = Ab + (tm + w * 16 + rl) * (long)lda + sl * 8;
  const u16* gB = Bb + (tn + w * 16 + rl) * (long)ldb + sl * 8;

  f32x4 acc[4][2] = {};

#define STAGE(AsX, BsX, kt_)                                                    \
  {                                                                             \
    const int k0_ = (kt_) * 64;                                                 \
    __builtin_amdgcn_global_load_lds(GAS(gA + k0_),            LAS(AsX + w * 1024),       16, 0, 0); \
    __builtin_amdgcn_global_load_lds(GAS(gA + k0_ + 8 * lda),  LAS(AsX + w * 1024 + 512), 16, 0, 0); \
    __builtin_amdgcn_global_load_lds(GAS(gB + k0_),            LAS(BsX + w * 1024),       16, 0, 0); \
    __builtin_amdgcn_global_load_lds(GAS(gB + k0_ + 8 * ldb),  LAS(BsX + w * 1024 + 512), 16, 0, 0); \
  }

#define COMPUTE(AsX, BsX)                                                       \
  {                                                                             \
    _Pragma("unroll")                                                           \
    for (int ks = 0; ks < 2; ++ks) {                                            \
      bf16x8 af[4], bfr[2];                                                     \
      _Pragma("unroll")                                                         \
      for (int mt = 0; mt < 4; ++mt) {                                          \
        int row = wm * 64 + mt * 16 + fr;                                       \
        int slot = (ks * 4 + fq) ^ (fr & 7);                                    \
        af[mt] = *(const bf16x8*)(AsX + row * 64 + slot * 8);                   \
      }                                                                         \
      _Pragma("unroll")                                                         \
      for (int nt = 0; nt < 2; ++nt) {                                          \
        int row = wn * 32 + nt * 16 + fr;                                       \
        int slot = (ks * 4 + fq) ^ (fr & 7);                                    \
        bfr[nt] = *(const bf16x8*)(BsX + row * 64 + slot * 8);                  \
      }                                                                         \
      _Pragma("unroll")                                                         \
      for (int mt = 0; mt < 4; ++mt)                                            \
        _Pragma("unroll")                                                       \
        for (int nt = 0; nt < 2; ++nt)                                          \
          acc[mt][nt] = __builtin_amdgcn_mfma_f32_16x16x32_bf16(af[mt], bfr[nt], acc[mt][nt], 0, 0, 0); \
    }                                                                           \
  }

  STAGE(As0, Bs0, 0);
  __syncthreads();  // buf0 ready (barrier drains vmcnt)
  for (int kt = 0; kt < kTiles; kt += 2) {
    if (kt + 1 < kTiles) STAGE(As1, Bs1, kt + 1);
    COMPUTE(As0, Bs0);
    __syncthreads();
    if (kt + 2 < kTiles) STAGE(As0, Bs0, kt + 2);
    COMPUTE(As1, Bs1);
    __syncthreads();
  }
#undef STAGE
#undef COMPUTE

  // epilogue: C/D layout col=lane&15, row=(lane>>4)*4+reg (verified m89/m91)
  const int cr = (lane >> 4) * 4;
  const int cc = lane & 15;
#pragma unroll
  for (int mt = 0; mt < 4; ++mt) {
#pragma unroll
    for (int nt = 0; nt < 2; ++nt) {
#pragma unroll
      for (int r = 0; r < 4; ++r) {
        float v = acc[mt][nt][r];
        long gm = tm + wm * 64 + mt * 16 + cr + r;
        long gn = tn + wn * 32 + nt * 16 + cc;
        if constexpr (EPI == EPI_QK_SPLIT_BF16) {
          if (gn < 1024) ((u16*)Cv )[gm * (long)ldc + gn]        = f2bf(v + bias [gn]);
          else           ((u16*)Cv2)[gm * (long)ldc + gn - 1024] = f2bf(v + bias2[gn - 1024]);
        } else if constexpr (EPI == EPI_BIAS_ROW_BF16) {
          ((u16*)Cv)[gm * (long)ldc + gn] = f2bf(v + bias[gm]);
        } else if constexpr (EPI == EPI_SCALE_F32) {
          ((float*)Cv)[coff + gm * ldc + gn] = v * scale;
        } else if constexpr (EPI == EPI_BIAS_COL_F32) {
          ((float*)Cv)[gm * (long)ldc + gn] = v + bias[gn];
        } else {  // EPI_RESHAPE_BF16: attn_out [h,s,d]->[s,h*d] faithful reshape
          long rr  = (gn >> 6) * 128 + (gm >> 4);
          long cc2 = ((gm & 15) << 6) + (gn & 63);
          ((u16*)Cv)[coff + rr * 1024 + cc2] = f2bf(v);
        }
      }
    }
  }
}

// ============ single persistent cooperative kernel: whole pipeline ===========
// 256 blocks x 512 threads, 1 block/CU (co-residency guaranteed), 64 KiB LDS.
// Stages separated by grid.sync() instead of kernel boundaries (~13us each).
__global__ __launch_bounds__(512, 2)
void fused_all(const float* __restrict__ q,  const float* __restrict__ wq,
               const float* __restrict__ bq, const float* __restrict__ wk,
               const float* __restrict__ bk, const float* __restrict__ wv,
               const float* __restrict__ bv, const float* __restrict__ wo,
               const float* __restrict__ bo, float* __restrict__ out,
               char* __restrict__ ws) {
  // workspace layout (same as previous rounds)
  u16*   Xb   = (u16*)(ws);                  // X bf16 [4096][1024]
  u16*   Wqkb = (u16*)(ws + 8388608);        // [2048][1024] (Wq rows 0-1023, Wk 1024-2047)
  u16*   Wvb  = (u16*)(ws + 12582912);
  u16*   Wob  = (u16*)(ws + 14680064);
  u16*   Qb   = (u16*)(ws + 16777216);       // [4096][1024]
  u16*   Kb   = (u16*)(ws + 25165824);       // [4096][1024]
  u16*   Vtb  = (u16*)(ws + 33554432);       // [1024][4096]
  u16*   Rb   = (u16*)(ws + 41943040);       // [2][2048][1024]
  float* Sc   = (float*)(ws + 50331648);     // [2][2048][2048] f32
  u16*   Wt   = (u16*)(ws + 83886080);       // [2][2048][2048] bf16

  __shared__ __align__(16) u16 smem[32768];  // 64 KiB
  u16* As0 = smem;         u16* As1 = smem + 8192;
  u16* Bs0 = smem + 16384; u16* Bs1 = smem + 24576;

  cg::grid_group grid = cg::this_grid();
  const int tid = threadIdx.x;
  const int bid = blockIdx.x;

  // ---- stage 0: f32 -> bf16 converts (1,048,576 8-elem units) ----
#pragma unroll
  for (int it = 0; it < 8; ++it) {
    long u = (long)it * 131072 + (long)bid * 512 + tid;
    const float* src; u16* dst; long e;
    if (u < 524288) { src = q; dst = Xb; e = u; }
    else {
      long v2 = u - 524288; int wsel = (int)(v2 >> 17); e = v2 & 131071;
      if      (wsel == 0) { src = wq; dst = Wqkb; }
      else if (wsel == 1) { src = wk; dst = Wqkb + 1048576; }
      else if (wsel == 2) { src = wv; dst = Wvb; }
      else                { src = wo; dst = Wob; }
    }
    const float4* xp = (const float4*)(src + e * 8);
    float4 a = xp[0], c = xp[1];
    uint4 o;
    o.x = pack2(a.x, a.y); o.y = pack2(a.z, a.w);
    o.z = pack2(c.x, c.y); o.w = pack2(c.z, c.w);
    *(uint4*)(dst + e * 8) = o;
  }
  grid.sync();

  // ---- stage 1: QKV projections (768 tile-jobs, 3 per block) ----
  for (int r = 0; r < 3; ++r) {
    const int job = bid + 256 * r;
    if (job < 512) {  // [Q|K] = X@[Wq;Wk]^T + bias  (M=4096,N=2048,K=1024)
      long tm = (long)(job & 31) * 128, tn = (long)(job >> 5) * 128;
      gemm_body<EPI_QK_SPLIT_BF16>(Xb, 1024, Wqkb, 1024, Qb, Kb, 0, 1024,
                                   bq, bk, 0.f, 16, tm, tn, As0, As1, Bs0, Bs1);
    } else {          // Vt = Wv@X^T + bv[row]  (M=1024,N=4096,K=1024)
      const int vb = job - 512;
      long tm = (long)(vb & 7) * 128, tn = (long)(vb >> 3) * 128;
      gemm_body<EPI_BIAS_ROW_BF16>(Wvb, 1024, Xb, 1024, Vtb, nullptr, 0, 4096,
                                   bv, nullptr, 0.f, 16, tm, tn, As0, As1, Bs0, Bs1);
    }
    __syncthreads();
  }
  grid.sync();

  // ---- stage 2: scores = (Q@K^T)/128 per batch (512 tile-jobs, 2/block) ----
  for (int r = 0; r < 2; ++r) {
    const int job = bid + 256 * r;
    const int bx = job & 15, by = (job >> 4) & 15, bz = job >> 8;
    long tm = (long)bx * 128, tn = (long)by * 128;
    gemm_body<EPI_SCALE_F32>(Qb + (long)bz * 2048 * 1024, 1024,
                             Kb + (long)bz * 2048 * 1024, 1024,
                             Sc, nullptr, (long)bz * 2048 * 2048, 2048,
                             nullptr, nullptr, 1.0f / 128.0f, 16, tm, tn,
                             As0, As1, Bs0, Bs1);
    __syncthreads();
  }
  grid.sync();

  // ---- stage 3: row softmax f32[4096][2048] -> bf16 (16 rows/block) ----
  {
    float* sred = (float*)smem;  // 16 floats scratch (LDS reuse, stage-fenced)
    const int lane = tid & 63, wv8 = tid >> 6;
    for (int r = 0; r < 16; ++r) {
      const long row = (long)bid * 16 + r;
      const float* src = Sc + row * 2048;
      u16* dst = Wt + row * 2048;
      float4 a = ((const float4*)src)[tid];
      float m = fmaxf(fmaxf(a.x, a.y), fmaxf(a.z, a.w));
#pragma unroll
      for (int o = 32; o > 0; o >>= 1) m = fmaxf(m, __shfl_xor(m, o));
      if (lane == 0) sred[wv8] = m;
      __syncthreads();
      m = sred[0];
#pragma unroll
      for (int i = 1; i < 8; ++i) m = fmaxf(m, sred[i]);
      float e0 = __expf(a.x - m), e1 = __expf(a.y - m);
      float e2 = __expf(a.z - m), e3 = __expf(a.w - m);
      float s = (e0 + e1) + (e2 + e3);
#pragma unroll
      for (int o = 32; o > 0; o >>= 1) s += __shfl_xor(s, o);
      if (lane == 0) sred[8 + wv8] = s;
      __syncthreads();
      s = sred[8];
#pragma unroll
      for (int i = 1; i < 8; ++i) s += sred[8 + i];
      float inv = 1.0f / s;
      uint2 o2;
      o2.x = pack2(e0 * inv, e1 * inv);
      o2.y = pack2(e2 * inv, e3 * inv);
      ((uint2*)dst)[tid] = o2;
      __syncthreads();  // protect sred before next row
    }
  }
  grid.sync();

  // ---- stage 4: AO = W@V, faithful-reshape epilogue (256 jobs, 1/block) ----
  {
    const int bx = bid & 15, by = (bid >> 4) & 7, bz = bid >> 7;
    long tm = (long)bx * 128, tn = (long)by * 128;
    gemm_body<EPI_RESHAPE_BF16>(Wt + (long)bz * 2048 * 2048, 2048,
                                Vtb + (long)bz * 2048, 4096,
                                Rb, nullptr, (long)bz * 2048 * 1024, 1024,
                                nullptr, nullptr, 0.f, 32, tm, tn,
                                As0, As1, Bs0, Bs1);
    __syncthreads();
  }
  grid.sync();

  // ---- stage 5: out = R@Wo^T + bo (256 jobs, 1/block, f32 out) ----
  {
    long tm = (long)(bid & 31) * 128, tn = (long)(bid >> 5) * 128;
    gemm_body<EPI_BIAS_COL_F32>(Rb, 1024, Wob, 1024, out, nullptr, 0, 1024,
                                bo, nullptr, 0.f, 16, tm, tn, As0, As1, Bs0, Bs1);
  }
}

// ---------------- launch ----------------
extern "C" void kernel_launch(void* const* d_in, const int* in_sizes, int n_in,
                              void* d_out, int out_size, void* d_ws, size_t ws_size,
                              hipStream_t stream) {
  const float* query = (const float*)d_in[0];
  const float* Wq = (const float*)d_in[1];
  const float* bq = (const float*)d_in[2];
  const float* Wk = (const float*)d_in[3];
  const float* bk = (const float*)d_in[4];
  const float* Wv = (const float*)d_in[5];
  const float* bv = (const float*)d_in[6];
  const float* Wo = (const float*)d_in[7];
  const float* bo = (const float*)d_in[8];
  float* out = (float*)d_out;
  char* ws = (char*)d_ws;

  void* args[] = {(void*)&query, (void*)&Wq, (void*)&bq, (void*)&Wk, (void*)&bk,
                  (void*)&Wv, (void*)&bv, (void*)&Wo, (void*)&bo,
                  (void*)&out, (void*)&ws};
  hipLaunchCooperativeKernel(reinterpret_cast<void*>(fused_all),
                             dim3(256), dim3(512), args, 0, stream);
}

// Round 7
// 225.851 us; speedup vs baseline: 1.8472x; 1.8472x over previous
//
#include <hip/hip_runtime.h>

typedef unsigned int   u32;
typedef unsigned short u16;
typedef short bf16x8 __attribute__((ext_vector_type(8)));
typedef float f32x4  __attribute__((ext_vector_type(4)));

#define GAS(p) ((const __attribute__((address_space(1))) void*)(p))
#define LAS(p) ((__attribute__((address_space(3))) void*)(p))

__device__ __forceinline__ u16 f2bf(float f) {
  union { float f; u32 u; } v; v.f = f;
  u32 r = v.u + 0x7fffu + ((v.u >> 16) & 1u);
  return (u16)(r >> 16);
}
__device__ __forceinline__ u32 pack2(float a, float b) {
  return (u32)f2bf(a) | ((u32)f2bf(b) << 16);
}

#define EPI_QK_SPLIT_BF16 0
#define EPI_BIAS_ROW_BF16 1
#define EPI_SCALE_F32     2
#define EPI_BIAS_COL_F32  3
#define EPI_RESHAPE_BF16  4

// ---------------- unified f32 -> bf16 convert (all 5 inputs, 1 launch) -------
__global__ __launch_bounds__(256) void cvt_all(
    const float* __restrict__ q,  const float* __restrict__ wq,
    const float* __restrict__ wk, const float* __restrict__ wv,
    const float* __restrict__ wo, u16* __restrict__ xb,
    u16* __restrict__ wqkb, u16* __restrict__ wvb, u16* __restrict__ wob) {
  const int b = blockIdx.x;
  const float* src; u16* dst; long off;
  if (b < 2048)      { src = q;  dst = xb;             off = (long)b * 2048; }
  else if (b < 2560) { src = wq; dst = wqkb;           off = (long)(b - 2048) * 2048; }
  else if (b < 3072) { src = wk; dst = wqkb + 1048576; off = (long)(b - 2560) * 2048; }
  else if (b < 3584) { src = wv; dst = wvb;            off = (long)(b - 3072) * 2048; }
  else               { src = wo; dst = wob;            off = (long)(b - 3584) * 2048; }
  const long i = off + (long)threadIdx.x * 8;
  const float4* xp = (const float4*)(src + i);
  float4 a = xp[0], c = xp[1];
  uint4 o;
  o.x = pack2(a.x, a.y); o.y = pack2(a.z, a.w);
  o.z = pack2(c.x, c.y); o.w = pack2(c.z, c.w);
  *(uint4*)(dst + i) = o;
}

// ======================= 8-phase 256x256 GEMM (m201 port) ====================
// C = A @ Bt^T. 8 waves (2M x 4N), per-wave out 128x64, BK=64, LDS 128 KiB
// (2 dbuf x (A 256x64 + B 256x64) bf16). Per K-tile: 4 quadrant-phases of
// 16 MFMA; each phase stages ONE half-tile (2 x global_load_lds) whose LDS
// region died in an earlier phase (A-pair0/B0 die after p1, B1 after p2,
// A-pair1 after p3; staged at p2/p3/p4/p5). vmcnt(6) only at phases 4/8 ->
// 3 half-tiles stay in flight across barriers (T3+T4). T5 setprio on MFMA.
// Raw s_barrier (NOT __syncthreads - no vmcnt drain). lgkmcnt(0)+sched_barrier
// before MFMA (rule 18). XOR-swizzle via pre-swizzled source (G4, rule 21).
template <int EPI>
__device__ __forceinline__
void gemm8_body(const u16* __restrict__ Ab, int lda,
                const u16* __restrict__ Bb, int ldb,
                void* __restrict__ Cv, void* __restrict__ Cv2, long coff, int ldc,
                const float* __restrict__ bias, const float* __restrict__ bias2,
                float scale, int kTiles, long tm, long tn, u16* lds) {
  u16* As0 = lds;          u16* As1 = lds + 16384;
  u16* Bs0 = lds + 32768;  u16* Bs1 = lds + 49152;

  const int lane = threadIdx.x & 63, w = threadIdx.x >> 6;
  const int wm = w >> 2, wn = w & 3;          // wave grid 2M x 4N
  const int rl = lane >> 3;                   // row-in-8-stripe this lane stages
  const int sl = (lane & 7) ^ rl;             // pre-swizzled 16B slot
  const int fr = lane & 15, fq = lane >> 4;
  const int w8 = w * 8;
  const int bb = (w & 3) * 8 + (w >> 2) * 64; // B stage base rows

  f32x4 acc[8][4] = {};
  bf16x8 a[4][2], b0[2][2], b1[2][2];

#define GLDS(ga, la) __builtin_amdgcn_global_load_lds(GAS(ga), LAS(la), 16, 0, 0)
  // half id g = tile*4 + h;  h: 0=A-pair0{0-63,128-191} 1=B0{wn*64+0..31}
  //                             2=B1{wn*64+32..63}      3=A-pair1{64-127,192-255}
#define STAGE_HALF(gg) do { const int t_ = (gg) >> 2; if (t_ < kTiles) {          \
    const int h_ = (gg) & 3; const long k0_ = (long)t_ * 64;                      \
    if (h_ == 0 || h_ == 3) {                                                     \
      u16* SA = (t_ & 1) ? As1 : As0; const int po = (h_ == 3) ? 64 : 0;          \
      GLDS(Ab + (tm + po + w8 + rl) * (long)lda + k0_ + sl * 8,                   \
           SA + (po + w8) * 64);                                                  \
      GLDS(Ab + (tm + po + 128 + w8 + rl) * (long)lda + k0_ + sl * 8,             \
           SA + (po + 128 + w8) * 64);                                            \
    } else {                                                                      \
      u16* SB = (t_ & 1) ? Bs1 : Bs0; const int off = (h_ == 1) ? 0 : 32;         \
      GLDS(Bb + (tn + bb + off + rl) * (long)ldb + k0_ + sl * 8,                  \
           SB + (bb + off) * 64);                                                 \
      GLDS(Bb + (tn + bb + off + 128 + rl) * (long)ldb + k0_ + sl * 8,            \
           SB + (bb + off + 128) * 64);                                           \
    } } } while (0)

#define READ_A(AT, msub) _Pragma("unroll") for (int mt = 0; mt < 4; ++mt)         \
    _Pragma("unroll") for (int ks = 0; ks < 2; ++ks)                              \
      a[mt][ks] = *(const bf16x8*)((AT) +                                         \
        (wm * 128 + (msub) * 64 + mt * 16 + fr) * 64 +                            \
        ((ks * 4 + fq) ^ (fr & 7)) * 8);
#define READ_B(BR, BT, h) _Pragma("unroll") for (int nt = 0; nt < 2; ++nt)        \
    _Pragma("unroll") for (int ks = 0; ks < 2; ++ks)                              \
      BR[nt][ks] = *(const bf16x8*)((BT) +                                        \
        (wn * 64 + (h) * 32 + nt * 16 + fr) * 64 +                                \
        ((ks * 4 + fq) ^ (fr & 7)) * 8);
#define CLUSTER(msub, bx, BR) _Pragma("unroll") for (int mt = 0; mt < 4; ++mt)    \
    _Pragma("unroll") for (int nt = 0; nt < 2; ++nt)                              \
    _Pragma("unroll") for (int ks = 0; ks < 2; ++ks)                              \
      acc[(msub) * 4 + mt][(bx) * 2 + nt] =                                       \
        __builtin_amdgcn_mfma_f32_16x16x32_bf16(a[mt][ks], BR[nt][ks],            \
            acc[(msub) * 4 + mt][(bx) * 2 + nt], 0, 0, 0);
#define BAR   asm volatile("s_barrier" ::: "memory")
#define LGKM0 do { asm volatile("s_waitcnt lgkmcnt(0)" ::: "memory");             \
                   __builtin_amdgcn_sched_barrier(0); } while (0)
#define PRIO1 __builtin_amdgcn_s_setprio(1)
#define PRIO0 __builtin_amdgcn_s_setprio(0)

  // prologue: tile0 all 4 halves + tile1 h0,h1,h2 ; confirm tile0 (6 = 3 halves fly)
  STAGE_HALF(0); STAGE_HALF(1); STAGE_HALF(2); STAGE_HALF(3);
  STAGE_HALF(4); STAGE_HALF(5); STAGE_HALF(6);
  asm volatile("s_waitcnt vmcnt(6)" ::: "memory");
  BAR;

  const int nIter = kTiles >> 1;  // kTiles must be even
  for (int i = 0; i < nIter; ++i) {
    const int g = 8 * i + 7;
    const bool last = (i == nIter - 1);
    // ---- K-tile 2i (As0/Bs0): phases 1-4 ----
    READ_A(As0, 0); READ_B(b0, Bs0, 0);
    STAGE_HALF(g + 0);
    BAR; LGKM0; PRIO1; CLUSTER(0, 0, b0); PRIO0; BAR;
    READ_B(b1, Bs0, 1);
    STAGE_HALF(g + 1);
    BAR; LGKM0; PRIO1; CLUSTER(0, 1, b1); PRIO0; BAR;
    READ_A(As0, 1);
    STAGE_HALF(g + 2);
    BAR; LGKM0; PRIO1; CLUSTER(1, 0, b0); PRIO0; BAR;
    STAGE_HALF(g + 3);
    BAR; PRIO1; CLUSTER(1, 1, b1); PRIO0;
    if (last) { asm volatile("s_waitcnt vmcnt(0)" ::: "memory"); }
    else      { asm volatile("s_waitcnt vmcnt(6)" ::: "memory"); }
    BAR;
    // ---- K-tile 2i+1 (As1/Bs1): phases 5-8 ----
    READ_A(As1, 0); READ_B(b0, Bs1, 0);
    STAGE_HALF(g + 4);
    BAR; LGKM0; PRIO1; CLUSTER(0, 0, b0); PRIO0; BAR;
    READ_B(b1, Bs1, 1);
    STAGE_HALF(g + 5);
    BAR; LGKM0; PRIO1; CLUSTER(0, 1, b1); PRIO0; BAR;
    READ_A(As1, 1);
    STAGE_HALF(g + 6);
    BAR; LGKM0; PRIO1; CLUSTER(1, 0, b0); PRIO0; BAR;
    STAGE_HALF(g + 7);
    BAR; PRIO1; CLUSTER(1, 1, b1); PRIO0;
    if (!last) { asm volatile("s_waitcnt vmcnt(6)" ::: "memory"); BAR; }
  }
#undef GLDS
#undef STAGE_HALF
#undef READ_A
#undef READ_B
#undef CLUSTER
#undef BAR
#undef LGKM0
#undef PRIO1
#undef PRIO0

  // epilogue: C/D layout col=lane&15, row=(lane>>4)*4+reg (verified m89/m91)
  const int cr = (lane >> 4) * 4, cc = lane & 15;
#pragma unroll
  for (int mtg = 0; mtg < 8; ++mtg) {
#pragma unroll
    for (int ntg = 0; ntg < 4; ++ntg) {
#pragma unroll
      for (int r = 0; r < 4; ++r) {
        float v = acc[mtg][ntg][r];
        long gm = tm + wm * 128 + mtg * 16 + cr + r;
        long gn = tn + wn * 64 + ntg * 16 + cc;
        if constexpr (EPI == EPI_QK_SPLIT_BF16) {
          if (gn < 1024) ((u16*)Cv )[gm * (long)ldc + gn]        = f2bf(v + bias [gn]);
          else           ((u16*)Cv2)[gm * (long)ldc + gn - 1024] = f2bf(v + bias2[gn - 1024]);
        } else if constexpr (EPI == EPI_BIAS_ROW_BF16) {
          ((u16*)Cv)[gm * (long)ldc + gn] = f2bf(v + bias[gm]);
        } else if constexpr (EPI == EPI_SCALE_F32) {
          ((float*)Cv)[coff + gm * ldc + gn] = v * scale;
        } else if constexpr (EPI == EPI_BIAS_COL_F32) {
          ((float*)Cv)[gm * (long)ldc + gn] = v + bias[gn];
        } else {
          long rr  = (gn >> 6) * 128 + (gm >> 4);
          long cc2 = ((gm & 15) << 6) + (gn & 63);
          ((u16*)Cv)[coff + rr * 1024 + cc2] = f2bf(v);
        }
      }
    }
  }
}

// QKV at 256^2: blocks 0..127 QK-proj (16x8), 128..191 V-proj (4x16)
__global__ __launch_bounds__(512, 2)
void k8_qkv(const u16* __restrict__ Xb, const u16* __restrict__ Wqkb,
            const u16* __restrict__ Wvb, u16* __restrict__ Qb, u16* __restrict__ Kb,
            u16* __restrict__ Vtb, const float* __restrict__ bq,
            const float* __restrict__ bk, const float* __restrict__ bv) {
  __shared__ __align__(16) u16 lds[65536];  // 128 KiB
  const int bid = blockIdx.x;
  if (bid < 128) {
    long tm = (long)(bid & 15) * 256, tn = (long)(bid >> 4) * 256;
    gemm8_body<EPI_QK_SPLIT_BF16>(Xb, 1024, Wqkb, 1024, Qb, Kb, 0, 1024,
                                  bq, bk, 0.f, 16, tm, tn, lds);
  } else {
    const int vb = bid - 128;
    long tm = (long)(vb & 3) * 256, tn = (long)(vb >> 2) * 256;
    gemm8_body<EPI_BIAS_ROW_BF16>(Wvb, 1024, Xb, 1024, Vtb, nullptr, 0, 4096,
                                  bv, nullptr, 0.f, 16, tm, tn, lds);
  }
}

template <int EPI>
__global__ __launch_bounds__(512, 2)
void k8_gemm(const u16* __restrict__ A, long sAz, int lda,
             const u16* __restrict__ Bt, long sBz, int ldb,
             void* __restrict__ Cv, long sCz, int ldc,
             const float* __restrict__ bias, float scale, int kTiles) {
  __shared__ __align__(16) u16 lds[65536];
  long tm = (long)blockIdx.x * 256, tn = (long)blockIdx.y * 256;
  gemm8_body<EPI>(A + (long)blockIdx.z * sAz, lda, Bt + (long)blockIdx.z * sBz, ldb,
                  Cv, nullptr, (long)blockIdx.z * sCz, ldc, bias, nullptr,
                  scale, kTiles, tm, tn, lds);
}

// =================== 2-phase 128x128 GEMM (round-4, proven) ==================
template <int EPI>
__device__ __forceinline__
void gemm_body(const u16* __restrict__ Ab, int lda,
               const u16* __restrict__ Bb, int ldb,
               void* __restrict__ Cv, void* __restrict__ Cv2, long coff, int ldc,
               const float* __restrict__ bias, const float* __restrict__ bias2,
               float scale, int kTiles, long tm, long tn,
               u16* As0, u16* As1, u16* Bs0, u16* Bs1) {
  const int tid = threadIdx.x, lane = tid & 63, w = tid >> 6;
  const int wm = w >> 2, wn = w & 3;
  const int rl = lane >> 3;
  const int sl = (lane & 7) ^ rl;
  const int fr = lane & 15, fq = lane >> 4;

  const u16* gA = Ab + (tm + w * 16 + rl) * (long)lda + sl * 8;
  const u16* gB = Bb + (tn + w * 16 + rl) * (long)ldb + sl * 8;

  f32x4 acc[4][2] = {};

#define STAGE(AsX, BsX, kt_)                                                    \
  {                                                                             \
    const int k0_ = (kt_) * 64;                                                 \
    __builtin_amdgcn_global_load_lds(GAS(gA + k0_),            LAS(AsX + w * 1024),       16, 0, 0); \
    __builtin_amdgcn_global_load_lds(GAS(gA + k0_ + 8 * lda),  LAS(AsX + w * 1024 + 512), 16, 0, 0); \
    __builtin_amdgcn_global_load_lds(GAS(gB + k0_),            LAS(BsX + w * 1024),       16, 0, 0); \
    __builtin_amdgcn_global_load_lds(GAS(gB + k0_ + 8 * ldb),  LAS(BsX + w * 1024 + 512), 16, 0, 0); \
  }

#define COMPUTE(AsX, BsX)                                                       \
  {                                                                             \
    _Pragma("unroll")                                                           \
    for (int ks = 0; ks < 2; ++ks) {                                            \
      bf16x8 af[4], bfr[2];                                                     \
      _Pragma("unroll")                                                         \
      for (int mt = 0; mt < 4; ++mt) {                                          \
        int row = wm * 64 + mt * 16 + fr;                                       \
        int slot = (ks * 4 + fq) ^ (fr & 7);                                    \
        af[mt] = *(const bf16x8*)(AsX + row * 64 + slot * 8);                   \
      }                                                                         \
      _Pragma("unroll")                                                         \
      for (int nt = 0; nt < 2; ++nt) {                                          \
        int row = wn * 32 + nt * 16 + fr;                                       \
        int slot = (ks * 4 + fq) ^ (fr & 7);                                    \
        bfr[nt] = *(const bf16x8*)(BsX + row * 64 + slot * 8);                  \
      }                                                                         \
      _Pragma("unroll")                                                         \
      for (int mt = 0; mt < 4; ++mt)                                            \
        _Pragma("unroll")                                                       \
        for (int nt = 0; nt < 2; ++nt)                                          \
          acc[mt][nt] = __builtin_amdgcn_mfma_f32_16x16x32_bf16(af[mt], bfr[nt], acc[mt][nt], 0, 0, 0); \
    }                                                                           \
  }

  STAGE(As0, Bs0, 0);
  __syncthreads();
  for (int kt = 0; kt < kTiles; kt += 2) {
    if (kt + 1 < kTiles) STAGE(As1, Bs1, kt + 1);
    COMPUTE(As0, Bs0);
    __syncthreads();
    if (kt + 2 < kTiles) STAGE(As0, Bs0, kt + 2);
    COMPUTE(As1, Bs1);
    __syncthreads();
  }
#undef STAGE
#undef COMPUTE

  const int cr = (lane >> 4) * 4;
  const int cc = lane & 15;
#pragma unroll
  for (int mt = 0; mt < 4; ++mt) {
#pragma unroll
    for (int nt = 0; nt < 2; ++nt) {
#pragma unroll
      for (int r = 0; r < 4; ++r) {
        float v = acc[mt][nt][r];
        long gm = tm + wm * 64 + mt * 16 + cr + r;
        long gn = tn + wn * 32 + nt * 16 + cc;
        if constexpr (EPI == EPI_QK_SPLIT_BF16) {
          if (gn < 1024) ((u16*)Cv )[gm * (long)ldc + gn]        = f2bf(v + bias [gn]);
          else           ((u16*)Cv2)[gm * (long)ldc + gn - 1024] = f2bf(v + bias2[gn - 1024]);
        } else if constexpr (EPI == EPI_BIAS_ROW_BF16) {
          ((u16*)Cv)[gm * (long)ldc + gn] = f2bf(v + bias[gm]);
        } else if constexpr (EPI == EPI_SCALE_F32) {
          ((float*)Cv)[coff + gm * ldc + gn] = v * scale;
        } else if constexpr (EPI == EPI_BIAS_COL_F32) {
          ((float*)Cv)[gm * (long)ldc + gn] = v + bias[gn];
        } else {
          long rr  = (gn >> 6) * 128 + (gm >> 4);
          long cc2 = ((gm & 15) << 6) + (gn & 63);
          ((u16*)Cv)[coff + rr * 1024 + cc2] = f2bf(v);
        }
      }
    }
  }
}

template <int EPI>
__global__ __launch_bounds__(512, 4)
void k_gemm(const u16* __restrict__ A, long sAz, int lda,
            const u16* __restrict__ Bt, long sBz, int ldb,
            void* __restrict__ Cv, long sCz, int ldc,
            const float* __restrict__ bias, float scale, int kTiles) {
  __shared__ __align__(16) u16 As[2][8192], Bs[2][8192];
  long tm = (long)blockIdx.x * 128, tn = (long)blockIdx.y * 128;
  gemm_body<EPI>(A + (long)blockIdx.z * sAz, lda, Bt + (long)blockIdx.z * sBz, ldb,
                 Cv, nullptr, (long)blockIdx.z * sCz, ldc, bias, nullptr,
                 scale, kTiles, tm, tn, As[0], As[1], Bs[0], Bs[1]);
}

// ---------------- row softmax: f32 [4096][2048] -> bf16 weights ----------------
__global__ __launch_bounds__(256) void softmax_k(const float* __restrict__ S,
                                                 u16* __restrict__ W) {
  const long row = blockIdx.x;
  const float* src = S + row * 2048;
  u16* dst = W + row * 2048;
  const int t = threadIdx.x, lane = t & 63, wid = t >> 6;

  const float4* sp = (const float4*)(src + t * 8);
  float4 a = sp[0], b = sp[1];
  float m = fmaxf(fmaxf(fmaxf(a.x, a.y), fmaxf(a.z, a.w)),
                  fmaxf(fmaxf(b.x, b.y), fmaxf(b.z, b.w)));
#pragma unroll
  for (int o = 32; o > 0; o >>= 1) m = fmaxf(m, __shfl_xor(m, o));
  __shared__ float redm[4], reds[4];
  if (lane == 0) redm[wid] = m;
  __syncthreads();
  m = fmaxf(fmaxf(redm[0], redm[1]), fmaxf(redm[2], redm[3]));

  float e[8];
  e[0] = __expf(a.x - m); e[1] = __expf(a.y - m);
  e[2] = __expf(a.z - m); e[3] = __expf(a.w - m);
  e[4] = __expf(b.x - m); e[5] = __expf(b.y - m);
  e[6] = __expf(b.z - m); e[7] = __expf(b.w - m);
  float s = ((e[0] + e[1]) + (e[2] + e[3])) + ((e[4] + e[5]) + (e[6] + e[7]));
#pragma unroll
  for (int o = 32; o > 0; o >>= 1) s += __shfl_xor(s, o);
  if (lane == 0) reds[wid] = s;
  __syncthreads();
  s = (reds[0] + reds[1]) + (reds[2] + reds[3]);
  float inv = 1.0f / s;

  uint4 o4;
  o4.x = pack2(e[0] * inv, e[1] * inv);
  o4.y = pack2(e[2] * inv, e[3] * inv);
  o4.z = pack2(e[4] * inv, e[5] * inv);
  o4.w = pack2(e[6] * inv, e[7] * inv);
  *(uint4*)(dst + t * 8) = o4;
}

// ---------------- launch ----------------
extern "C" void kernel_launch(void* const* d_in, const int* in_sizes, int n_in,
                              void* d_out, int out_size, void* d_ws, size_t ws_size,
                              hipStream_t stream) {
  const float* query = (const float*)d_in[0];
  const float* Wq = (const float*)d_in[1];
  const float* bq = (const float*)d_in[2];
  const float* Wk = (const float*)d_in[3];
  const float* bk = (const float*)d_in[4];
  const float* Wv = (const float*)d_in[5];
  const float* bv = (const float*)d_in[6];
  const float* Wo = (const float*)d_in[7];
  const float* bo = (const float*)d_in[8];
  float* out = (float*)d_out;

  char* ws = (char*)d_ws;
  u16*   Xb   = (u16*)(ws);                  // query bf16 [4096][1024]
  u16*   Wqkb = (u16*)(ws + 8388608);        // [2048][1024]
  u16*   Wvb  = (u16*)(ws + 12582912);
  u16*   Wob  = (u16*)(ws + 14680064);
  u16*   Qb   = (u16*)(ws + 16777216);       // [4096][1024]
  u16*   Kb   = (u16*)(ws + 25165824);       // [4096][1024]
  u16*   Vtb  = (u16*)(ws + 33554432);       // [1024][4096]
  u16*   Rb   = (u16*)(ws + 41943040);       // [2][2048][1024]
  float* Sc   = (float*)(ws + 50331648);     // [2][2048][2048] f32
  u16*   Wt   = (u16*)(ws + 83886080);       // [2][2048][2048] bf16

  cvt_all<<<4096, 256, 0, stream>>>(query, Wq, Wk, Wv, Wo, Xb, Wqkb, Wvb, Wob);

  // QKV: 8-phase 256^2 (192 tile-jobs)
  k8_qkv<<<192, 512, 0, stream>>>(Xb, Wqkb, Wvb, Qb, Kb, Vtb, bq, bk, bv);

  // scores = (Q@K^T)/128 per batch: 8-phase 256^2 (128 tile-jobs)
  k8_gemm<EPI_SCALE_F32><<<dim3(8, 8, 2), 512, 0, stream>>>(
      Qb, 2048L * 1024, 1024, Kb, 2048L * 1024, 1024,
      Sc, 2048L * 2048, 2048, nullptr, 1.0f / 128.0f, 16);

  softmax_k<<<4096, 256, 0, stream>>>(Sc, Wt);

  // AO = W@V per batch (K=2048), faithful-reshape epilogue: 2-phase 128^2
  k_gemm<EPI_RESHAPE_BF16><<<dim3(16, 8, 2), 512, 0, stream>>>(
      Wt, 2048L * 2048, 2048, Vtb, 2048, 4096,
      Rb, 2048L * 1024, 1024, nullptr, 0.f, 32);

  // out = R@Wo^T + bo: 2-phase 128^2
  k_gemm<EPI_BIAS_COL_F32><<<dim3(32, 8, 1), 512, 0, stream>>>(
      Rb, 0, 1024, Wob, 0, 1024, out, 0, 1024, bo, 0.f, 16);
}

// Round 8
// 199.867 us; speedup vs baseline: 2.0874x; 1.1300x over previous
//
#include <hip/hip_runtime.h>

typedef unsigned int   u32;
typedef unsigned short u16;
typedef short bf16x8 __attribute__((ext_vector_type(8)));
typedef float f32x4  __attribute__((ext_vector_type(4)));

#define GAS(p) ((const __attribute__((address_space(1))) void*)(p))
#define LAS(p) ((__attribute__((address_space(3))) void*)(p))

__device__ __forceinline__ u16 f2bf(float f) {
  union { float f; u32 u; } v; v.f = f;
  u32 r = v.u + 0x7fffu + ((v.u >> 16) & 1u);
  return (u16)(r >> 16);
}
__device__ __forceinline__ u32 pack2(float a, float b) {
  return (u32)f2bf(a) | ((u32)f2bf(b) << 16);
}

#define EPI_QK_SPLIT_BF16 0
#define EPI_BIAS_ROW_BF16 1
#define EPI_SCALE_F32     2
#define EPI_BIAS_COL_F32  3
#define EPI_RESHAPE_BF16  4

// ---------------- unified f32 -> bf16 convert (all 5 inputs, 1 launch) -------
__global__ __launch_bounds__(256) void cvt_all(
    const float* __restrict__ q,  const float* __restrict__ wq,
    const float* __restrict__ wk, const float* __restrict__ wv,
    const float* __restrict__ wo, u16* __restrict__ xb,
    u16* __restrict__ wqkb, u16* __restrict__ wvb, u16* __restrict__ wob) {
  const int b = blockIdx.x;
  const float* src; u16* dst; long off;
  if (b < 2048)      { src = q;  dst = xb;             off = (long)b * 2048; }
  else if (b < 2560) { src = wq; dst = wqkb;           off = (long)(b - 2048) * 2048; }
  else if (b < 3072) { src = wk; dst = wqkb + 1048576; off = (long)(b - 2560) * 2048; }
  else if (b < 3584) { src = wv; dst = wvb;            off = (long)(b - 3072) * 2048; }
  else               { src = wo; dst = wob;            off = (long)(b - 3584) * 2048; }
  const long i = off + (long)threadIdx.x * 8;
  const float4* xp = (const float4*)(src + i);
  float4 a = xp[0], c = xp[1];
  uint4 o;
  o.x = pack2(a.x, a.y); o.y = pack2(a.z, a.w);
  o.z = pack2(c.x, c.y); o.w = pack2(c.z, c.w);
  *(uint4*)(dst + i) = o;
}

// ========== counted-vmcnt 2-phase 128x128 GEMM: C = A @ Bt^T (+epi) ==========
// 8 waves, 128x128 tile, BK=64, wave grid 2Mx4N, wave-tile 64x32, acc[4][2].
// T4 at tile granularity: per tile {ds_read ALL frags -> lgkmcnt(0)+schedbar ->
// s_barrier (buf dead) -> STAGE(buf, kt+2) -> MFMA(regs) -> vmcnt(4) ->
// s_barrier (tile kt+1 collectively landed)}. vmcnt NEVER 0 in-loop: the next
// tile's loads span two barriers and a full MFMA phase (unlike __syncthreads,
// which drains the prefetch at every barrier - round-4's hidden flaw).
// Invariant: 4 own loads outstanding at iter entry. MFMA order identical to
// round 4 -> bitwise-identical results (absmax must stay 4.882812e-4).
// LDS XOR-swizzle via pre-swizzled source + swizzled ds_read (G4, rule 21).
template <int EPI>
__device__ __forceinline__
void gemm_body(const u16* __restrict__ Ab, int lda,
               const u16* __restrict__ Bb, int ldb,
               void* __restrict__ Cv, void* __restrict__ Cv2, long coff, int ldc,
               const float* __restrict__ bias, const float* __restrict__ bias2,
               float scale, int kTiles, long tm, long tn,
               u16* As0, u16* As1, u16* Bs0, u16* Bs1) {
  const int tid = threadIdx.x, lane = tid & 63, w = tid >> 6;
  const int wm = w >> 2, wn = w & 3;      // wave grid 2x4
  const int rl = lane >> 3;               // row-in-stripe this lane stages
  const int sl = (lane & 7) ^ rl;         // pre-swizzled 16B-slot index
  const int fr = lane & 15, fq = lane >> 4;

  const u16* gA = Ab + (tm + w * 16 + rl) * (long)lda + sl * 8;
  const u16* gB = Bb + (tn + w * 16 + rl) * (long)ldb + sl * 8;

  f32x4 acc[4][2] = {};
  bf16x8 af[4][2], bfr[2][2];             // full tile's frags (held across bar)

#define STAGE(AsX, BsX, kt_)                                                    \
  {                                                                             \
    const int k0_ = (kt_) * 64;                                                 \
    __builtin_amdgcn_global_load_lds(GAS(gA + k0_),            LAS(AsX + w * 1024),       16, 0, 0); \
    __builtin_amdgcn_global_load_lds(GAS(gA + k0_ + 8 * lda),  LAS(AsX + w * 1024 + 512), 16, 0, 0); \
    __builtin_amdgcn_global_load_lds(GAS(gB + k0_),            LAS(BsX + w * 1024),       16, 0, 0); \
    __builtin_amdgcn_global_load_lds(GAS(gB + k0_ + 8 * ldb),  LAS(BsX + w * 1024 + 512), 16, 0, 0); \
  }

#define READF(AsX, BsX)                                                         \
  {                                                                             \
    _Pragma("unroll")                                                           \
    for (int mt = 0; mt < 4; ++mt)                                              \
      _Pragma("unroll")                                                         \
      for (int ks = 0; ks < 2; ++ks)                                            \
        af[mt][ks] = *(const bf16x8*)((AsX) + (wm * 64 + mt * 16 + fr) * 64 +   \
                                      ((ks * 4 + fq) ^ (fr & 7)) * 8);          \
    _Pragma("unroll")                                                           \
    for (int nt = 0; nt < 2; ++nt)                                              \
      _Pragma("unroll")                                                         \
      for (int ks = 0; ks < 2; ++ks)                                            \
        bfr[nt][ks] = *(const bf16x8*)((BsX) + (wn * 32 + nt * 16 + fr) * 64 +  \
                                       ((ks * 4 + fq) ^ (fr & 7)) * 8);         \
  }

#define MFMAS                                                                   \
  {                                                                             \
    __builtin_amdgcn_s_setprio(1);                                              \
    _Pragma("unroll")                                                           \
    for (int ks = 0; ks < 2; ++ks)                                              \
      _Pragma("unroll")                                                         \
      for (int mt = 0; mt < 4; ++mt)                                            \
        _Pragma("unroll")                                                       \
        for (int nt = 0; nt < 2; ++nt)                                          \
          acc[mt][nt] = __builtin_amdgcn_mfma_f32_16x16x32_bf16(af[mt][ks], bfr[nt][ks], acc[mt][nt], 0, 0, 0); \
    __builtin_amdgcn_s_setprio(0);                                              \
  }

#define LGKM0_SB do { asm volatile("s_waitcnt lgkmcnt(0)" ::: "memory");        \
                      __builtin_amdgcn_sched_barrier(0);                        \
                      asm volatile("s_barrier" ::: "memory"); } while (0)
#define VM_SB(n) do { asm volatile("s_waitcnt vmcnt(" #n ")" ::: "memory");     \
                      asm volatile("s_barrier" ::: "memory"); } while (0)

  // prologue: stage tiles 0,1; confirm tile 0 collectively (tile 1 stays flying)
  STAGE(As0, Bs0, 0);
  STAGE(As1, Bs1, 1);
  VM_SB(4);

  for (int kt = 0; kt < kTiles; kt += 2) {
    // ---- tile kt from buf0 ----
    READF(As0, Bs0);
    LGKM0_SB;                              // all waves hold buf0 in regs
    if (kt + 2 < kTiles) STAGE(As0, Bs0, kt + 2);
    MFMAS;
    if (kt + 2 < kTiles) VM_SB(4); else VM_SB(0);  // tile kt+1 ready
    // ---- tile kt+1 from buf1 ----
    READF(As1, Bs1);
    LGKM0_SB;                              // all waves hold buf1 in regs
    if (kt + 3 < kTiles) STAGE(As1, Bs1, kt + 3);
    MFMAS;
    if (kt + 2 < kTiles) {                 // not last iter: confirm tile kt+2
      if (kt + 3 < kTiles) VM_SB(4); else VM_SB(0);
    }
  }
#undef STAGE
#undef READF
#undef MFMAS
#undef LGKM0_SB
#undef VM_SB

  // epilogue: C/D layout col=lane&15, row=(lane>>4)*4+reg (verified m89/m91)
  const int cr = (lane >> 4) * 4;
  const int cc = lane & 15;
#pragma unroll
  for (int mt = 0; mt < 4; ++mt) {
#pragma unroll
    for (int nt = 0; nt < 2; ++nt) {
#pragma unroll
      for (int r = 0; r < 4; ++r) {
        float v = acc[mt][nt][r];
        long gm = tm + wm * 64 + mt * 16 + cr + r;
        long gn = tn + wn * 32 + nt * 16 + cc;
        if constexpr (EPI == EPI_QK_SPLIT_BF16) {
          if (gn < 1024) ((u16*)Cv )[gm * (long)ldc + gn]        = f2bf(v + bias [gn]);
          else           ((u16*)Cv2)[gm * (long)ldc + gn - 1024] = f2bf(v + bias2[gn - 1024]);
        } else if constexpr (EPI == EPI_BIAS_ROW_BF16) {
          ((u16*)Cv)[gm * (long)ldc + gn] = f2bf(v + bias[gm]);
        } else if constexpr (EPI == EPI_SCALE_F32) {
          ((float*)Cv)[coff + gm * ldc + gn] = v * scale;
        } else if constexpr (EPI == EPI_BIAS_COL_F32) {
          ((float*)Cv)[gm * (long)ldc + gn] = v + bias[gn];
        } else {  // EPI_RESHAPE_BF16: attn_out [h,s,d]->[s,h*d] faithful reshape
          long rr  = (gn >> 6) * 128 + (gm >> 4);
          long cc2 = ((gm & 15) << 6) + (gn & 63);
          ((u16*)Cv)[coff + rr * 1024 + cc2] = f2bf(v);
        }
      }
    }
  }
}

// merged QK-projection (jobs 0..511) + V-projection (jobs 512..767),
// XCD-aware swizzle (768 % 8 == 0 -> bijective chunked remap, T1)
__global__ __launch_bounds__(512, 4)
void k_qkv(const u16* __restrict__ Xb, const u16* __restrict__ Wqkb,
           const u16* __restrict__ Wvb, u16* __restrict__ Qb, u16* __restrict__ Kb,
           u16* __restrict__ Vtb, const float* __restrict__ bq,
           const float* __restrict__ bk, const float* __restrict__ bv) {
  __shared__ __align__(16) u16 As[2][8192], Bs[2][8192];
  const int b = blockIdx.x;
  const int job = (b & 7) * 96 + (b >> 3);
  if (job < 512) {
    long tm = (long)(job & 31) * 128, tn = (long)(job >> 5) * 128;
    gemm_body<EPI_QK_SPLIT_BF16>(Xb, 1024, Wqkb, 1024, Qb, Kb, 0, 1024,
                                 bq, bk, 0.f, 16, tm, tn, As[0], As[1], Bs[0], Bs[1]);
  } else {
    const int vb = job - 512;
    long tm = (long)(vb & 7) * 128, tn = (long)(vb >> 3) * 128;
    gemm_body<EPI_BIAS_ROW_BF16>(Wvb, 1024, Xb, 1024, Vtb, nullptr, 0, 4096,
                                 bv, nullptr, 0.f, 16, tm, tn, As[0], As[1], Bs[0], Bs[1]);
  }
}

template <int EPI>
__global__ __launch_bounds__(512, 4)
void k_gemm(const u16* __restrict__ A, long sAz, int lda,
            const u16* __restrict__ Bt, long sBz, int ldb,
            void* __restrict__ Cv, long sCz, int ldc,
            const float* __restrict__ bias, float scale, int kTiles) {
  __shared__ __align__(16) u16 As[2][8192], Bs[2][8192];
  long tm = (long)blockIdx.x * 128, tn = (long)blockIdx.y * 128;
  gemm_body<EPI>(A + (long)blockIdx.z * sAz, lda, Bt + (long)blockIdx.z * sBz, ldb,
                 Cv, nullptr, (long)blockIdx.z * sCz, ldc, bias, nullptr,
                 scale, kTiles, tm, tn, As[0], As[1], Bs[0], Bs[1]);
}

// ---------------- row softmax: f32 [4096][2048] -> bf16 weights ----------------
__global__ __launch_bounds__(256) void softmax_k(const float* __restrict__ S,
                                                 u16* __restrict__ W) {
  const long row = blockIdx.x;
  const float* src = S + row * 2048;
  u16* dst = W + row * 2048;
  const int t = threadIdx.x, lane = t & 63, wid = t >> 6;

  const float4* sp = (const float4*)(src + t * 8);
  float4 a = sp[0], b = sp[1];
  float m = fmaxf(fmaxf(fmaxf(a.x, a.y), fmaxf(a.z, a.w)),
                  fmaxf(fmaxf(b.x, b.y), fmaxf(b.z, b.w)));
#pragma unroll
  for (int o = 32; o > 0; o >>= 1) m = fmaxf(m, __shfl_xor(m, o));
  __shared__ float redm[4], reds[4];
  if (lane == 0) redm[wid] = m;
  __syncthreads();
  m = fmaxf(fmaxf(redm[0], redm[1]), fmaxf(redm[2], redm[3]));

  float e[8];
  e[0] = __expf(a.x - m); e[1] = __expf(a.y - m);
  e[2] = __expf(a.z - m); e[3] = __expf(a.w - m);
  e[4] = __expf(b.x - m); e[5] = __expf(b.y - m);
  e[6] = __expf(b.z - m); e[7] = __expf(b.w - m);
  float s = ((e[0] + e[1]) + (e[2] + e[3])) + ((e[4] + e[5]) + (e[6] + e[7]));
#pragma unroll
  for (int o = 32; o > 0; o >>= 1) s += __shfl_xor(s, o);
  if (lane == 0) reds[wid] = s;
  __syncthreads();
  s = (reds[0] + reds[1]) + (reds[2] + reds[3]);
  float inv = 1.0f / s;

  uint4 o4;
  o4.x = pack2(e[0] * inv, e[1] * inv);
  o4.y = pack2(e[2] * inv, e[3] * inv);
  o4.z = pack2(e[4] * inv, e[5] * inv);
  o4.w = pack2(e[6] * inv, e[7] * inv);
  *(uint4*)(dst + t * 8) = o4;
}

// ---------------- launch ----------------
extern "C" void kernel_launch(void* const* d_in, const int* in_sizes, int n_in,
                              void* d_out, int out_size, void* d_ws, size_t ws_size,
                              hipStream_t stream) {
  const float* query = (const float*)d_in[0];
  const float* Wq = (const float*)d_in[1];
  const float* bq = (const float*)d_in[2];
  const float* Wk = (const float*)d_in[3];
  const float* bk = (const float*)d_in[4];
  const float* Wv = (const float*)d_in[5];
  const float* bv = (const float*)d_in[6];
  const float* Wo = (const float*)d_in[7];
  const float* bo = (const float*)d_in[8];
  float* out = (float*)d_out;

  char* ws = (char*)d_ws;
  u16*   Xb   = (u16*)(ws);                  // query bf16 [4096][1024]
  u16*   Wqkb = (u16*)(ws + 8388608);        // [2048][1024]
  u16*   Wvb  = (u16*)(ws + 12582912);
  u16*   Wob  = (u16*)(ws + 14680064);
  u16*   Qb   = (u16*)(ws + 16777216);       // [4096][1024]
  u16*   Kb   = (u16*)(ws + 25165824);       // [4096][1024]
  u16*   Vtb  = (u16*)(ws + 33554432);       // [1024][4096]
  u16*   Rb   = (u16*)(ws + 41943040);       // [2][2048][1024]
  float* Sc   = (float*)(ws + 50331648);     // [2][2048][2048] f32
  u16*   Wt   = (u16*)(ws + 83886080);       // [2][2048][2048] bf16

  cvt_all<<<4096, 256, 0, stream>>>(query, Wq, Wk, Wv, Wo, Xb, Wqkb, Wvb, Wob);

  // [Q|K] = X@[Wq;Wk]^T + bias  AND  Vt = Wv@X^T + bv   (768 tiles = 3 rounds)
  k_qkv<<<768, 512, 0, stream>>>(Xb, Wqkb, Wvb, Qb, Kb, Vtb, bq, bk, bv);

  // scores = (Q@K^T)/128 per batch (512 tiles = 2 rounds)
  k_gemm<EPI_SCALE_F32><<<dim3(16, 16, 2), 512, 0, stream>>>(
      Qb, 2048L * 1024, 1024, Kb, 2048L * 1024, 1024,
      Sc, 2048L * 2048, 2048, nullptr, 1.0f / 128.0f, 16);

  softmax_k<<<4096, 256, 0, stream>>>(Sc, Wt);

  // AO = W@V per batch (K=2048), faithful-reshape epilogue (256 tiles)
  k_gemm<EPI_RESHAPE_BF16><<<dim3(16, 8, 2), 512, 0, stream>>>(
      Wt, 2048L * 2048, 2048, Vtb, 2048, 4096,
      Rb, 2048L * 1024, 1024, nullptr, 0.f, 32);

  // out = R@Wo^T + bo (256 tiles)
  k_gemm<EPI_BIAS_COL_F32><<<dim3(32, 8, 1), 512, 0, stream>>>(
      Rb, 0, 1024, Wob, 0, 1024, out, 0, 1024, bo, 0.f, 16);
}